// Round 6
// baseline (133.926 us; speedup 1.0000x reference)
//
#include <hip/hip_runtime.h>
#include <stdint.h>

// Simple exponential smoothing: level_t = (1-a)*level_{t-1} + a*y_t,
// level_0 = y_0 pinned via global initial carry s_{-1} = y_0.
// out[t] = level_t for t in [0, n-2].
//
// 3-pass reduce-then-scan, SEG=16 (R6: short dependent chains + 100% occupancy;
// R5's SEG=64 emit was latency-bound at 2.5x its traffic floor).
//   pass 1: per-block affine aggregate (G=4096 tiles of 4096 elems)
//   pass 2: 1-block scan of G aggregates -> per-tile carry (measured ~3us)
//   pass 3: emit; replay from registers, LDS-staged coalesced float4 stores
//           (R3-verified: kills write amplification, 206MB -> 65.7MB)
// No cross-block atomics (R2: ~80us agent-scope spin cost), no cooperative
// launch (R4: rejected under graph capture).
//
// Affine pairs (a,b): s_out = a*s_in + b.
// combine(earlier=(a1,b1), later=(a2,b2)) = (a1*a2, a2*b1 + b2).

#define BLOCK 256
#define SEG   16                  // elements per thread
#define VPT   (SEG / 4)           // float4 per thread = 4
#define CHUNK (BLOCK * SEG)       // 4096 elements per block
#define ROWS  65                  // padded LDS row stride -> max 2-way bank alias (free)

// Inclusive Hillis-Steele scan over BLOCK affine pairs in LDS.
__device__ __forceinline__ void block_scan_affine(float* sa, float* sb, int t) {
#pragma unroll
    for (int off = 1; off < BLOCK; off <<= 1) {
        float pa = 1.0f, pb = 0.0f;
        if (t >= off) { pa = sa[t - off]; pb = sb[t - off]; }
        __syncthreads();
        if (t >= off) {
            float ca = sa[t], cb = sb[t];
            sa[t] = pa * ca;
            sb[t] = fmaf(ca, pb, cb);
        }
        __syncthreads();
    }
}

// Pass 1: per-block affine aggregate.
__global__ __launch_bounds__(BLOCK, 8) void k_block_agg(
    const float* __restrict__ y, const float* __restrict__ alpha_p,
    float* __restrict__ aggA, float* __restrict__ aggB, long n)
{
    const int t = threadIdx.x;
    const long base = (long)blockIdx.x * CHUNK + (long)t * SEG;
    const float alpha = alpha_p[0];
    const float oma = 1.0f - alpha;

    float a = 1.0f, s = 0.0f;
    if (base + SEG <= n) {
        const float4* p = (const float4*)(y + base);
#pragma unroll
        for (int v = 0; v < VPT; ++v) {
            float4 q = p[v];
            s = fmaf(oma, s, alpha * q.x);
            s = fmaf(oma, s, alpha * q.y);
            s = fmaf(oma, s, alpha * q.z);
            s = fmaf(oma, s, alpha * q.w);
        }
        a = __powf(oma, (float)SEG);
    } else {
        for (int k = 0; k < SEG; ++k) {
            long idx = base + k;
            if (idx < n) { s = fmaf(oma, s, alpha * y[idx]); a *= oma; }
        }
    }

    __shared__ float sa[BLOCK], sb[BLOCK];
    sa[t] = a; sb[t] = s;
    __syncthreads();
    block_scan_affine(sa, sb, t);
    if (t == BLOCK - 1) {
        aggA[blockIdx.x] = sa[t];
        aggB[blockIdx.x] = sb[t];
    }
}

// Pass 2: single block scans the G aggregates -> per-tile carry.
__global__ __launch_bounds__(BLOCK) void k_carry_scan(
    const float* __restrict__ aggA, const float* __restrict__ aggB,
    const float* __restrict__ y, float* __restrict__ carry, int G)
{
    const int t = threadIdx.x;
    const int items = (G + BLOCK - 1) / BLOCK;   // 16 for G=4096
    const float y0 = y[0];

    float ta = 1.0f, tb = 0.0f;
    for (int j = 0; j < items; ++j) {
        int g = t * items + j;
        if (g < G) {
            float ca = aggA[g], cb = aggB[g];
            tb = fmaf(ca, tb, cb);
            ta *= ca;
        }
    }

    __shared__ float sa[BLOCK], sb[BLOCK];
    sa[t] = ta; sb[t] = tb;
    __syncthreads();
    block_scan_affine(sa, sb, t);

    float ea = 1.0f, eb = 0.0f;
    if (t > 0) { ea = sa[t - 1]; eb = sb[t - 1]; }
    for (int j = 0; j < items; ++j) {
        int g = t * items + j;
        if (g < G) {
            carry[g] = fmaf(ea, y0, eb);
            float ca = aggA[g], cb = aggB[g];
            eb = fmaf(ca, eb, cb);
            ea *= ca;
        }
    }
}

// Pass 3: emit. Register-cached tile, block scan, replay, LDS-staged stores.
__global__ __launch_bounds__(BLOCK, 8) void k_emit(
    const float* __restrict__ y, const float* __restrict__ alpha_p,
    const float* __restrict__ carry, float* __restrict__ out, long n)
{
    __shared__ float sa[BLOCK], sb[BLOCK];
    __shared__ float stage[64 * ROWS];      // 16640 B; ~18.8 KB total -> 8 blocks/CU

    const int t = threadIdx.x;
    const long tbase = (long)blockIdx.x * CHUNK;
    const long base  = tbase + (long)t * SEG;
    const float alpha = alpha_p[0];
    const float oma   = 1.0f - alpha;
    const float c     = carry[blockIdx.x];   // ready since pass 2
    const bool fullTile = (tbase + CHUNK <= n);

    float4 arr[VPT];
    float a_seg, b_seg;

    if (fullTile) {
        const float4* p = (const float4*)(y + base);
#pragma unroll
        for (int v = 0; v < VPT; ++v) arr[v] = p[v];
        float s = 0.0f;
#pragma unroll
        for (int v = 0; v < VPT; ++v) {
            s = fmaf(oma, s, alpha * arr[v].x);
            s = fmaf(oma, s, alpha * arr[v].y);
            s = fmaf(oma, s, alpha * arr[v].z);
            s = fmaf(oma, s, alpha * arr[v].w);
        }
        b_seg = s;
        a_seg = __powf(oma, (float)SEG);     // |err| ~ulp, irrelevant vs 2e-2 threshold
    } else {
        float a = 1.0f, s = 0.0f;
        for (int k = 0; k < SEG; ++k) {
            long idx = base + k;
            if (idx < n) { s = fmaf(oma, s, alpha * y[idx]); a *= oma; }
        }
        a_seg = a; b_seg = s;
    }

    sa[t] = a_seg; sb[t] = b_seg;
    __syncthreads();
    block_scan_affine(sa, sb, t);

    float ea = 1.0f, eb = 0.0f;
    if (t > 0) { ea = sa[t - 1]; eb = sb[t - 1]; }
    float lvl = fmaf(ea, c, eb);            // level just before this thread's segment

    if (fullTile) {
        // replay in registers
#pragma unroll
        for (int v = 0; v < VPT; ++v) {
            float4 q4 = arr[v], r;
            lvl = fmaf(oma, lvl, alpha * q4.x); r.x = lvl;
            lvl = fmaf(oma, lvl, alpha * q4.y); r.y = lvl;
            lvl = fmaf(oma, lvl, alpha * q4.z); r.z = lvl;
            lvl = fmaf(oma, lvl, alpha * q4.w); r.w = lvl;
            arr[v] = r;
        }
        // single-phase staging: thread t -> row t>>2, cols (t&3)*16 .. +15
        {
            float* row = &stage[(t >> 2) * ROWS + ((t & 3) << 4)];
#pragma unroll
            for (int v = 0; v < VPT; ++v) {
                row[4 * v + 0] = arr[v].x;
                row[4 * v + 1] = arr[v].y;
                row[4 * v + 2] = arr[v].z;
                row[4 * v + 3] = arr[v].w;
            }
        }
        __syncthreads();
        const bool lastGuard = (tbase + CHUNK > n - 1);
#pragma unroll
        for (int k = 0; k < 4; ++k) {
            int jj = t + (k << 8);             // float4 idx 0..1023
            int g  = jj >> 4;                  // source row
            int e  = (jj << 2) & 63;           // col within row
            const float* row = &stage[g * ROWS + e];
            float4 r;
            r.x = row[0]; r.y = row[1]; r.z = row[2]; r.w = row[3];
            long gi = tbase + 4 * (long)jj;
            if (!lastGuard) {
                *(float4*)(out + gi) = r;
            } else {
                if (gi + 4 <= n - 1) {
                    *(float4*)(out + gi) = r;
                } else {
                    if (gi + 0 < n - 1) out[gi + 0] = r.x;
                    if (gi + 1 < n - 1) out[gi + 1] = r.y;
                    if (gi + 2 < n - 1) out[gi + 2] = r.z;
                    if (gi + 3 < n - 1) out[gi + 3] = r.w;
                }
            }
        }
    } else {
        for (int k = 0; k < SEG; ++k) {
            long idx = base + k;
            if (idx < n) {
                lvl = fmaf(oma, lvl, alpha * y[idx]);
                if (idx < n - 1) out[idx] = lvl;
            }
        }
    }
}

extern "C" void kernel_launch(void* const* d_in, const int* in_sizes, int n_in,
                              void* d_out, int out_size, void* d_ws, size_t ws_size,
                              hipStream_t stream) {
    const float* y     = (const float*)d_in[0];
    const float* alpha = (const float*)d_in[1];
    float* out = (float*)d_out;
    const long n = (long)in_sizes[0];
    const int  G = (int)((n + CHUNK - 1) / CHUNK);   // 4096 for n = 2^24

    float* aggA  = (float*)d_ws;       // G floats
    float* aggB  = aggA + G;           // G floats
    float* carry = aggB + G;           // G floats (all fully written before read)

    k_block_agg<<<G, BLOCK, 0, stream>>>(y, alpha, aggA, aggB, n);
    k_carry_scan<<<1, BLOCK, 0, stream>>>(aggA, aggB, y, carry, G);
    k_emit<<<G, BLOCK, 0, stream>>>(y, alpha, carry, out, n);
}